// Round 2
// baseline (1962.963 us; speedup 1.0000x reference)
//
#include <hip/hip_runtime.h>
#include <math.h>

#define B_DIM 64
#define C_DIM 768
#define S_DIM 1024   // 32*32 spatial
#define E_DIM 64
#define NBLK  12288  // (64*768 rows) * 64 lanes / 256 threads
#define NFIN  64     // last NFIN ticket-holders run the gate, one batch each

// ---------------------------------------------------------------------------
// Fused kernel: phase 1 = global average pool (one wave per (b,c) row),
// phase 2 (last 64 tickets) = gate: sigmoid(pooled @ W^T + b), top-K on
// biased scores, gather original, normalize.
// Device-scope ticketing: __threadfence + atomicAdd; finishers spin until
// counter == NBLK (finishers increment BEFORE spinning, so no deadlock;
// <=64 spinners on 256 CUs cannot starve the remaining blocks).
// ---------------------------------------------------------------------------
__global__ __launch_bounds__(256) void fused_gate_kernel(
        const float* __restrict__ x,
        const float* __restrict__ Wm,
        const float* __restrict__ bvec,
        const float* __restrict__ route_bias,
        int K,
        float* __restrict__ pooled,          // d_ws: B*C floats
        unsigned int* __restrict__ counter,  // d_ws: 1 uint, pre-zeroed
        float* __restrict__ out) {
    __shared__ __align__(16) float s_pool[C_DIM];
    __shared__ float s_scores[E_DIM];
    __shared__ unsigned int s_ticket;

    const int tid  = threadIdx.x;
    const int lane = tid & 63;

    // ---------------- phase 1: pool one (b,c) row per wave ----------------
    {
        int row = (int)(blockIdx.x * 4 + (tid >> 6));   // 0 .. 49151
        const float4* p = (const float4*)(x + (size_t)row * S_DIM);
        float s = 0.0f;
#pragma unroll
        for (int k = 0; k < 4; ++k) {
            float4 v = p[k * 64 + lane];
            s += (v.x + v.y) + (v.z + v.w);
        }
#pragma unroll
        for (int off = 1; off < 64; off <<= 1) s += __shfl_xor(s, off);
        if (lane == 0) pooled[row] = s * (1.0f / (float)S_DIM);
    }

    // ---------------- ticket: device-scope release + count ----------------
    __threadfence();                 // make pooled[] visible device-wide
    if (tid == 0) s_ticket = atomicAdd(counter, 1u);
    __syncthreads();
    const unsigned int ticket = s_ticket;
    if (ticket < (unsigned)(NBLK - NFIN)) return;   // block-uniform exit
    const int b = (int)ticket - (NBLK - NFIN);      // my batch row

    // wait until ALL blocks have published their pooled rows
    if (tid == 0) {
        while (__hip_atomic_load(counter, __ATOMIC_ACQUIRE,
                                 __HIP_MEMORY_SCOPE_AGENT) < (unsigned)NBLK) {
            __builtin_amdgcn_s_sleep(8);
        }
    }
    __syncthreads();
    __threadfence();                 // acquire: order pooled[] reads after spin

    // ---------------- phase 2: gate for batch b ----------------
    // stage pooled[b,:] into LDS (coalesced)
    const float* prow = pooled + (size_t)b * C_DIM;
    for (int i = tid; i < C_DIM; i += 256) s_pool[i] = prow[i];
    __syncthreads();

    // dot product: expert e handled by 4 consecutive threads (q = chunk)
    const int e = tid >> 2;      // 0..63
    const int q = tid & 3;       // 0..3, each covers 192 channels
    const float4* wrow  = (const float4*)(Wm + (size_t)e * C_DIM + q * 192);
    const float4* prow4 = (const float4*)(s_pool + q * 192);
    float acc = 0.0f;
#pragma unroll 8
    for (int i = 0; i < 48; ++i) {
        float4 wv = wrow[i];
        float4 pv = prow4[i];
        acc += wv.x * pv.x + wv.y * pv.y + wv.z * pv.z + wv.w * pv.w;
    }
    acc += __shfl_xor(acc, 1);
    acc += __shfl_xor(acc, 2);
    if (q == 0) {
        float z = acc + bvec[e];
        s_scores[e] = 1.0f / (1.0f + expf(-z));
    }
    __syncthreads();

    // top-K selection + normalization by wave 0
    if (tid < 64) {
        float myval = s_scores[lane] + route_bias[lane];  // biased (selection)
        int sel_idx = 0;
        bool have_sel = false;

        for (int k = 0; k < K; ++k) {
            float v = myval;
            int   i = lane;
#pragma unroll
            for (int off = 1; off < 64; off <<= 1) {
                float ov = __shfl_xor(v, off);
                int   oi = __shfl_xor(i, off);
                // argmax, tie-break to smaller index (lax.top_k semantics)
                if (ov > v || (ov == v && oi < i)) { v = ov; i = oi; }
            }
            if (lane == k) { sel_idx = i; have_sel = true; }
            if (lane == i) myval = -INFINITY;   // remove winner
        }

        float w = have_sel ? s_scores[sel_idx] : 0.0f;  // original score
        float tot = w;
#pragma unroll
        for (int off = 1; off < 64; off <<= 1) tot += __shfl_xor(tot, off);

        if (lane < K) {
            // weights [B,K] then indices [B,K] (as float), flat in d_out
            out[(size_t)b * K + lane] = w / tot;  // ROUTE_SCALE == 1.0
            out[(size_t)B_DIM * K + (size_t)b * K + lane] = (float)sel_idx;
        }
    }
}

extern "C" void kernel_launch(void* const* d_in, const int* in_sizes, int n_in,
                              void* d_out, int out_size, void* d_ws, size_t ws_size,
                              hipStream_t stream) {
    const float* x          = (const float*)d_in[0];
    const float* Wm         = (const float*)d_in[1];
    const float* bvec       = (const float*)d_in[2];
    const float* route_bias = (const float*)d_in[3];
    const int K = out_size / (2 * B_DIM);   // = 8

    float*        pooled  = (float*)d_ws;                       // 49152 floats
    unsigned int* counter = (unsigned int*)((float*)d_ws + B_DIM * C_DIM);
    float*        out     = (float*)d_out;

    // zero the ticket counter (d_ws is poisoned 0xAA before every launch)
    hipMemsetAsync(counter, 0, sizeof(unsigned int), stream);

    fused_gate_kernel<<<NBLK, 256, 0, stream>>>(x, Wm, bvec, route_bias, K,
                                                pooled, counter, out);
}

// Round 3
// 284.301 us; speedup vs baseline: 6.9045x; 6.9045x over previous
//
#include <hip/hip_runtime.h>
#include <math.h>

#define B_DIM 64
#define C_DIM 768
#define S_DIM 1024   // 32*32 spatial
#define E_DIM 64

// ---------------------------------------------------------------------------
// Kernel 1: global average pool. One 64-lane wave per (b,c) row of 1024 floats.
// Each lane loads 4 float4 (coalesced, 16B/lane), wave shfl reduction.
// HBM-bound: 201 MB read -> ~32 us floor at 6.3 TB/s.
// ---------------------------------------------------------------------------
__global__ __launch_bounds__(256) void pool_kernel(const float* __restrict__ x,
                                                   float* __restrict__ pooled,
                                                   int nrows) {
    int wave = (int)((blockIdx.x * blockDim.x + threadIdx.x) >> 6);
    int lane = threadIdx.x & 63;
    if (wave >= nrows) return;

    const float4* p = (const float4*)(x + (size_t)wave * S_DIM);
    float s = 0.0f;
#pragma unroll
    for (int k = 0; k < 4; ++k) {
        float4 v = p[k * 64 + lane];
        s += (v.x + v.y) + (v.z + v.w);
    }
#pragma unroll
    for (int off = 1; off < 64; off <<= 1) s += __shfl_xor(s, off);
    if (lane == 0) pooled[wave] = s * (1.0f / (float)S_DIM);
}

// ---------------------------------------------------------------------------
// Kernel 2: per batch row: scores = sigmoid(pooled @ W^T + b); top-K on
// scores + route_bias; gather original scores; normalize; write out.
// Block = 256 threads, grid = B. 4 threads per expert for the 768-dot.
// ---------------------------------------------------------------------------
__global__ __launch_bounds__(256) void gate_kernel(const float* __restrict__ pooled,
                                                   const float* __restrict__ Wm,
                                                   const float* __restrict__ bvec,
                                                   const float* __restrict__ route_bias,
                                                   int K,
                                                   float* __restrict__ out) {
    __shared__ __align__(16) float s_pool[C_DIM];
    __shared__ float s_scores[E_DIM];

    const int b   = blockIdx.x;
    const int tid = threadIdx.x;

    // stage pooled[b,:] into LDS (coalesced)
    const float* prow = pooled + (size_t)b * C_DIM;
    for (int i = tid; i < C_DIM; i += 256) s_pool[i] = prow[i];
    __syncthreads();

    // dot product: expert e handled by 4 consecutive threads (q = chunk)
    const int e = tid >> 2;      // 0..63
    const int q = tid & 3;       // 0..3, each covers 192 channels
    const float4* wrow  = (const float4*)(Wm + (size_t)e * C_DIM + q * 192);
    const float4* prow4 = (const float4*)(s_pool + q * 192);
    float acc = 0.0f;
#pragma unroll 8
    for (int i = 0; i < 48; ++i) {
        float4 wv = wrow[i];
        float4 pv = prow4[i];
        acc += wv.x * pv.x + wv.y * pv.y + wv.z * pv.z + wv.w * pv.w;
    }
    // combine the 4 partials (consecutive lanes in the same wave)
    acc += __shfl_xor(acc, 1);
    acc += __shfl_xor(acc, 2);
    if (q == 0) {
        float z = acc + bvec[e];
        s_scores[e] = 1.0f / (1.0f + expf(-z));
    }
    __syncthreads();

    // top-K selection + normalization by wave 0
    if (tid < 64) {
        const int lane = tid;
        float myval = s_scores[lane] + route_bias[lane];  // biased (selection)
        int sel_idx = 0;
        bool have_sel = false;

        for (int k = 0; k < K; ++k) {
            float v = myval;
            int   i = lane;
#pragma unroll
            for (int off = 1; off < 64; off <<= 1) {
                float ov = __shfl_xor(v, off);
                int   oi = __shfl_xor(i, off);
                // argmax with tie-break to smaller index (lax.top_k semantics)
                if (ov > v || (ov == v && oi < i)) { v = ov; i = oi; }
            }
            if (lane == k) { sel_idx = i; have_sel = true; }
            if (lane == i) myval = -INFINITY;   // remove winner
        }

        float w = have_sel ? s_scores[sel_idx] : 0.0f;  // original score
        float tot = w;
#pragma unroll
        for (int off = 1; off < 64; off <<= 1) tot += __shfl_xor(tot, off);

        if (lane < K) {
            // weights [B,K] then indices [B,K] (as float), flat in d_out
            out[(size_t)b * K + lane] = w / tot;  // ROUTE_SCALE == 1.0
            out[(size_t)B_DIM * K + (size_t)b * K + lane] = (float)sel_idx;
        }
    }
}

extern "C" void kernel_launch(void* const* d_in, const int* in_sizes, int n_in,
                              void* d_out, int out_size, void* d_ws, size_t ws_size,
                              hipStream_t stream) {
    const float* x          = (const float*)d_in[0];
    const float* Wm         = (const float*)d_in[1];
    const float* bvec       = (const float*)d_in[2];
    const float* route_bias = (const float*)d_in[3];
    // d_in[4] is topk (device scalar); K also derivable from out_size:
    const int K = out_size / (2 * B_DIM);   // = 8

    float* pooled = (float*)d_ws;           // B*C floats = 196 KB
    float* out    = (float*)d_out;

    const int nrows  = B_DIM * C_DIM;                 // 49152 waves
    const int blocks = (nrows * 64 + 255) / 256;      // 12288
    pool_kernel<<<blocks, 256, 0, stream>>>(x, pooled, nrows);
    gate_kernel<<<B_DIM, 256, 0, stream>>>(pooled, Wm, bvec, route_bias, K, out);
}